// Round 17
// baseline (128.411 us; speedup 1.0000x reference)
//
#include <hip/hip_runtime.h>
#include <stdint.h>

#define TT 2048
#define BB 2
#define MROWS (BB*TT)
#define LSCALE 0.18033688011112043f   // 0.125 * log2(e)

typedef unsigned short u16;
typedef __bf16 bf16x8 __attribute__((ext_vector_type(8)));
typedef float f32x4 __attribute__((ext_vector_type(4)));
typedef short s16x8 __attribute__((ext_vector_type(8)));
typedef unsigned short u16x4 __attribute__((ext_vector_type(4)));

#define GLOBAL_AS const __attribute__((address_space(1))) void*
#define LDS_AS __attribute__((address_space(3))) void*

__device__ __forceinline__ u16 f2b(float f){
  uint32_t u = __builtin_bit_cast(uint32_t, f);
  u = (u + 0x7FFFu + ((u >> 16) & 1u)) >> 16;
  return (u16)u;
}

// ---------------- fused prep: one dispatch, all independent blocks ----------------
__global__ __launch_bounds__(256) void prep(
    const float* __restrict__ x, const float* __restrict__ Wq,
    const float* __restrict__ Wc, const float* __restrict__ bq,
    const float* __restrict__ Wk, const float* __restrict__ Wv,
    const float* __restrict__ Wo,
    u16* __restrict__ xb, u16* __restrict__ WqcT, u16* __restrict__ WkT,
    u16* __restrict__ WvT, u16* __restrict__ WoT, float* __restrict__ bqc){
  const int i = blockIdx.x, t = threadIdx.x;
  if (i < 4096){                      // x -> bf16 (16B/thread)
    int id = i * 256 + t;
    float4 v = ((const float4*)x)[id];
    u16x4 o; o.x = f2b(v.x); o.y = f2b(v.y); o.z = f2b(v.z); o.w = f2b(v.w);
    ((u16x4*)xb)[id] = o;
    return;
  }
  if (i < 7168){                      // f32->bf16 transpose of Wk/Wv/Wo
    int j = i - 4096;
    int z = j >> 10, rem = j & 1023;
    const float* in = (z == 0) ? Wk : (z == 1) ? Wv : Wo;
    u16* out = (z == 0) ? WkT : (z == 1) ? WvT : WoT;
    __shared__ float tl[32][33];
    int tx = t & 31, ty = t >> 5;
    int c0 = (rem & 31) * 32, r0 = (rem >> 5) * 32;
    #pragma unroll
    for (int k = 0; k < 32; k += 8)
      tl[ty + k][tx] = in[(size_t)(r0 + ty + k) * 1024 + c0 + tx];
    __syncthreads();
    #pragma unroll
    for (int k = 0; k < 32; k += 8)
      out[(size_t)(c0 + ty + k) * 1024 + r0 + tx] = f2b(tl[tx][ty + k]);
    return;
  }
  __shared__ float wc[4096];          // whole Wc (64x64 f32)
  #pragma unroll
  for (int k = 0; k < 16; ++k) wc[k * 256 + t] = Wc[k * 256 + t];
  __syncthreads();
  if (i == 7424){                     // folded bias bqc = bq @ Wc-blockdiag
    #pragma unroll
    for (int k = 0; k < 4; ++k){
      int nn = t * 4 + k;
      int h = nn >> 6, lc = nn & 63;
      float a = 0.f;
      #pragma unroll
      for (int dd = 0; dd < 64; ++dd) a += bq[h * 64 + dd] * wc[dd * 64 + lc];
      bqc[nn] = a;
    }
    return;
  }
  // Wqc fold, 64d x 64n tile, written transposed: WqcT[n][d]
  __shared__ float tile[64][65];
  const int j = i - 7168;             // 0..255
  const int db = j >> 4, hb = j & 15;
  {
    int dl = t >> 2, lq = t & 3;
    const float4* wq4 = (const float4*)(Wq + (size_t)(db * 64 + dl) * 1024 + hb * 64);
    float wqr[64];
    #pragma unroll
    for (int k = 0; k < 16; ++k){
      float4 v = wq4[k];
      wqr[k * 4] = v.x; wqr[k * 4 + 1] = v.y; wqr[k * 4 + 2] = v.z; wqr[k * 4 + 3] = v.w;
    }
    #pragma unroll
    for (int jj = 0; jj < 16; ++jj){
      int lc = lq * 16 + jj;
      float a = 0.f;
      #pragma unroll
      for (int dd = 0; dd < 64; ++dd) a += wqr[dd] * wc[dd * 64 + lc];
      tile[dl][lc] = a;
    }
  }
  __syncthreads();
  {
    int nl = t >> 2, dq = t & 3;
    u16* dst = WqcT + (size_t)(hb * 64 + nl) * 1024 + db * 64 + dq * 16;
    #pragma unroll
    for (int k = 0; k < 16; ++k)
      dst[k] = f2b(tile[dq * 16 + k][nl]);
  }
}

// vt[bh][d][s] = vb[b*T + s][h*64 + d]   (bf16 -> bf16 transpose per head)
__global__ void transpose_v(const u16* __restrict__ vb, u16* __restrict__ vt){
  __shared__ u16 t[32][34];
  int tx = threadIdx.x & 31, ty = threadIdx.x >> 5;
  int s0 = blockIdx.x * 32, d0 = blockIdx.y * 32, bh = blockIdx.z;
  int b = bh >> 4, h = bh & 15;
  #pragma unroll
  for (int i = 0; i < 32; i += 8)
    t[ty + i][tx] = vb[(size_t)(b * TT + s0 + ty + i) * 1024 + h * 64 + d0 + tx];
  __syncthreads();
  #pragma unroll
  for (int i = 0; i < 32; i += 8)
    vt[((size_t)bh * 64 + d0 + ty + i) * TT + s0 + tx] = t[tx][ty + i];
}

// ---------------- 128x128 bf16 MFMA GEMM tile (m97 structure) ----------------
__device__ __forceinline__ void gemm_tile(const u16* __restrict__ A, const u16* __restrict__ BT,
                                          int m0, int n0, int K, f32x4 (&acc)[4][4],
                                          u16* As, u16* Bs, int tid){
  const int wv = tid >> 6, l = tid & 63;
  const int aoff = ((wv >> 1) * 64 + (l & 15)) * 32 + ((l >> 4) << 3);
  const int boff = ((wv & 1) * 64 + (l & 15)) * 32 + ((l >> 4) << 3);
  const int ob0 = wv * 1024 + l * 16;           // byte offset in 8KB tile
  for (int kt = 0; kt < K; kt += 32){
    __syncthreads();
    #pragma unroll
    for (int j = 0; j < 2; ++j){
      int ob = ob0 + j * 4096;
      int row = ob >> 6, col = (ob & 63) >> 1;  // col in elements (mult of 8)
      __builtin_amdgcn_global_load_lds((GLOBAL_AS)(A + (size_t)(m0 + row) * 1024 + kt + col),
                                       (LDS_AS)(As + wv * 512 + j * 2048), 16, 0, 0);
      __builtin_amdgcn_global_load_lds((GLOBAL_AS)(BT + (size_t)(n0 + row) * 1024 + kt + col),
                                       (LDS_AS)(Bs + wv * 512 + j * 2048), 16, 0, 0);
    }
    __syncthreads();
    bf16x8 av[4], bw[4];
    #pragma unroll
    for (int m = 0; m < 4; ++m) av[m] = *(const bf16x8*)(As + aoff + m * 512);
    #pragma unroll
    for (int n = 0; n < 4; ++n) bw[n] = *(const bf16x8*)(Bs + boff + n * 512);
    #pragma unroll
    for (int m = 0; m < 4; ++m)
      #pragma unroll
      for (int n = 0; n < 4; ++n)
        acc[m][n] = __builtin_amdgcn_mfma_f32_16x16x32_bf16(av[m], bw[n], acc[m][n], 0, 0, 0);
  }
}

// fused QKV projections (z: 0=Qc pre-scaled, 1=K, 2=V row-major)
__global__ __launch_bounds__(256) void gemm_qkv(
    const u16* __restrict__ xb,
    const u16* __restrict__ W0T, const u16* __restrict__ W1T, const u16* __restrict__ W2T,
    const float* __restrict__ b0, const float* __restrict__ b1, const float* __restrict__ b2,
    u16* __restrict__ o0, u16* __restrict__ o1, u16* __restrict__ o2){
  __shared__ u16 As[4096], Bs[4096];
  const int z = blockIdx.z;
  const u16* BT = (z == 0) ? W0T : (z == 1) ? W1T : W2T;
  const float* bias = (z == 0) ? b0 : (z == 1) ? b1 : b2;
  u16* Out = (z == 0) ? o0 : (z == 1) ? o1 : o2;
  const float osc = (z == 0) ? LSCALE : 1.0f;   // fold softmax scale into Q
  const int n0 = blockIdx.x * 128, m0 = blockIdx.y * 128;
  const int tid = threadIdx.x, wv = tid >> 6, l = tid & 63;
  f32x4 acc[4][4] = {};
  gemm_tile(xb, BT, m0, n0, 1024, acc, As, Bs, tid);
  const int wr = wv >> 1, wc = wv & 1;
  #pragma unroll
  for (int n = 0; n < 4; ++n){
    int col = n0 + wc * 64 + n * 16 + (l & 15);
    float bb = bias[col];
    #pragma unroll
    for (int m = 0; m < 4; ++m){
      int r0 = m0 + wr * 64 + m * 16 + ((l >> 4) << 2);
      #pragma unroll
      for (int r = 0; r < 4; ++r)
        Out[(size_t)(r0 + r) * 1024 + col] = f2b((acc[m][n][r] + bb) * osc);
    }
  }
}

// ---------------- 64x128 out-projection GEMM (2 blocks/CU occupancy fix) ------
__global__ __launch_bounds__(256) void gemm_o(
    const u16* __restrict__ A, const u16* __restrict__ BT,
    const float* __restrict__ bias, float* __restrict__ Out){
  __shared__ u16 As[2048], Bs[4096];   // 4KB A (64x32), 8KB B (128x32)
  const int n0 = blockIdx.x * 128, m0 = blockIdx.y * 64;
  const int tid = threadIdx.x, wv = tid >> 6, l = tid & 63;
  const int wr = wv >> 1, wc = wv & 1;
  const int aoff = (wr * 32 + (l & 15)) * 32 + ((l >> 4) << 3);
  const int boff = (wc * 64 + (l & 15)) * 32 + ((l >> 4) << 3);
  const int obA = wv * 1024 + l * 16;
  const int rowA = obA >> 6, colA = (obA & 63) >> 1;
  const int ob0 = wv * 1024 + l * 16;
  f32x4 acc[2][4] = {};
  for (int kt = 0; kt < 1024; kt += 32){
    __syncthreads();
    __builtin_amdgcn_global_load_lds((GLOBAL_AS)(A + (size_t)(m0 + rowA) * 1024 + kt + colA),
                                     (LDS_AS)(As + wv * 512), 16, 0, 0);
    #pragma unroll
    for (int j = 0; j < 2; ++j){
      int ob = ob0 + j * 4096;
      int row = ob >> 6, col = (ob & 63) >> 1;
      __builtin_amdgcn_global_load_lds((GLOBAL_AS)(BT + (size_t)(n0 + row) * 1024 + kt + col),
                                       (LDS_AS)(Bs + wv * 512 + j * 2048), 16, 0, 0);
    }
    __syncthreads();
    bf16x8 av[2], bw[4];
    #pragma unroll
    for (int m = 0; m < 2; ++m) av[m] = *(const bf16x8*)(As + aoff + m * 512);
    #pragma unroll
    for (int n = 0; n < 4; ++n) bw[n] = *(const bf16x8*)(Bs + boff + n * 512);
    #pragma unroll
    for (int m = 0; m < 2; ++m)
      #pragma unroll
      for (int n = 0; n < 4; ++n)
        acc[m][n] = __builtin_amdgcn_mfma_f32_16x16x32_bf16(av[m], bw[n], acc[m][n], 0, 0, 0);
  }
  #pragma unroll
  for (int n = 0; n < 4; ++n){
    int col = n0 + wc * 64 + n * 16 + (l & 15);
    float bb = bias[col];
    #pragma unroll
    for (int m = 0; m < 2; ++m){
      int r0 = m0 + wr * 32 + m * 16 + ((l >> 4) << 2);
      #pragma unroll
      for (int r = 0; r < 4; ++r)
        Out[(size_t)(r0 + r) * 1024 + col] = acc[m][n][r] + bb;
    }
  }
}

// ---------------- flash attention (causal, per (b,h)) ----------------
// BQ=32 (2 waves x 16 q-rows), BS=64, single-buffer K/V staging (20KB LDS ->
// 8 blocks/CU). Per-wave work identical to BQ=64 (total wave-tiles conserved);
// 2x blocks/CU gives 2x independent chains to hide each block's vmcnt drain.
// qgtab: serpentine deal of qg 63..0 into 8 CU-bins -> every bin = 132 tiles.
// bh = idx&31 keeps 4 heads per XCD (L2-resident K/V).
__device__ const uint8_t qgtab[64] = {
  63, 62, 61, 60, 59, 58, 57, 56,
  48, 49, 50, 51, 52, 53, 54, 55,
  47, 46, 45, 44, 43, 42, 41, 40,
  32, 33, 34, 35, 36, 37, 38, 39,
  31, 30, 29, 28, 27, 26, 25, 24,
  16, 17, 18, 19, 20, 21, 22, 23,
  15, 14, 13, 12, 11, 10,  9,  8,
   0,  1,  2,  3,  4,  5,  6,  7
};

__global__ __launch_bounds__(128) void attn(
    const u16* __restrict__ qcg, const u16* __restrict__ kg,
    const u16* __restrict__ vtg, u16* __restrict__ yg){
  __shared__ u16 Ks[4096], Vs[4096];   // one 64-s tile each, XOR-swizzled chunks
  __shared__ u16 Ps[2048];             // per-wave 16 q-rows x 64 s
  const int idx = blockIdx.x;
  const int qg = qgtab[idx >> 5], bh = idx & 31;
  const int b = bh >> 4, h = bh & 15;
  const int q0 = qg * 32;
  const int tid = threadIdx.x, wv = tid >> 6, l = tid & 63;
  const int c4 = l >> 4, q16 = l & 15;
  const size_t base = (size_t)b * TT * 1024 + h * 64;
  const u16* Q = qcg + base;
  const u16* K = kg + base;
  const u16* Vt = vtg + (size_t)bh * 64 * TT;     // [64 d][T s]

  // staging: 128 threads, 4 insts/operand/tile (16 rows per inst)
  const int sr = tid >> 3;                         // 0..15
  const int sc = (tid & 7) ^ (sr & 7);             // row-parity XOR (j*16 = 0 mod 8)
  const u16* gK = K + (size_t)sr * 1024 + sc * 8;
  const u16* gV = Vt + (size_t)sr * TT + sc * 8;

  bf16x8 qf[2];
  {
    int qr = q0 + wv * 16 + q16;
    #pragma unroll
    for (int ks = 0; ks < 2; ++ks)
      qf[ks] = *(const bf16x8*)(Q + (size_t)qr * 1024 + ks * 32 + (c4 << 3));
  }
  // ones fragment for sum-via-MFMA (bf16 1.0 = 0x3F80)
  bf16x8 ones;
  {
    s16x8 o1;
    #pragma unroll
    for (int j = 0; j < 8; ++j) o1[j] = (short)0x3F80;
    ones = __builtin_bit_cast(bf16x8, o1);
  }
  f32x4 yacc[4] = {};                  // y^T: yacc[df][r] = y[q=q16][d=df*16+c4*4+r]
  f32x4 sacc = {};                     // sum row: sacc[0] = sum_s P[s][q]
  float mrow = -1e30f;                 // per-lane softmax max for q = l&15

  uint32_t* const PsW = (uint32_t*)Ps + wv * 512 + q16 * 32;
  const int pm = (q16 & 7) << 2;

  const int nt = (qg >> 1) + 1;
  for (int st = 0; st < nt; ++st){
    {
      const size_t o = (size_t)st * 64;
      #pragma unroll
      for (int j = 0; j < 4; ++j){
        __builtin_amdgcn_global_load_lds((GLOBAL_AS)(gK + (o + j * 16) * 1024),
                                         (LDS_AS)(Ks + j * 1024 + wv * 512), 16, 0, 0);
        __builtin_amdgcn_global_load_lds((GLOBAL_AS)(gV + o + (size_t)j * 16 * TT),
                                         (LDS_AS)(Vs + j * 1024 + wv * 512), 16, 0, 0);
      }
    }
    asm volatile("s_waitcnt vmcnt(0)" ::: "memory");
    __builtin_amdgcn_sched_barrier(0);
    __builtin_amdgcn_s_barrier();
    __builtin_amdgcn_sched_barrier(0);
    const int s0 = st * 64;
    f32x4 sf[4] = {};
    __builtin_amdgcn_s_setprio(1);
    #pragma unroll
    for (int ks = 0; ks < 2; ++ks)
      #pragma unroll
      for (int nf = 0; nf < 4; ++nf){
        int r = nf * 16 + q16, c = ks * 4 + c4;
        bf16x8 kf = *(const bf16x8*)(Ks + (r * 8 + (c ^ (r & 7))) * 8);
        sf[nf] = __builtin_amdgcn_mfma_f32_16x16x32_bf16(kf, qf[ks], sf[nf], 0, 0, 0);
      }
    __builtin_amdgcn_s_setprio(0);
    const int qa = q0 + wv * 16 + q16;
    float p[4][4];
    const bool domask = (st == nt - 1);
    #pragma unroll
    for (int nf = 0; nf < 4; ++nf)
      #pragma unroll
      for (int r = 0; r < 4; ++r){
        float v_ = sf[nf][r];
        if (domask && (s0 + nf * 16 + c4 * 4 + r > qa)) v_ = -1e30f;
        p[nf][r] = v_;
      }
    // max chain
    float tmax = fmaxf(fmaxf(p[0][0], p[0][1]), p[0][2]);
    tmax = fmaxf(fmaxf(tmax, p[0][3]), p[1][0]);
    tmax = fmaxf(fmaxf(tmax, p[1][1]), p[1][2]);
    tmax = fmaxf(fmaxf(tmax, p[1][3]), p[2][0]);
    tmax = fmaxf(fmaxf(tmax, p[2][1]), p[2][2]);
    tmax = fmaxf(fmaxf(tmax, p[2][3]), p[3][0]);
    tmax = fmaxf(fmaxf(tmax, p[3][1]), p[3][2]);
    tmax = fmaxf(tmax, p[3][3]);
    tmax = fmaxf(tmax, __shfl_xor(tmax, 16));
    tmax = fmaxf(tmax, __shfl_xor(tmax, 32));
    if (__any(tmax > mrow + 8.0f)){
      float mnew = fmaxf(mrow, tmax);
      float resc = exp2f(mrow - mnew);
      sacc[0] *= resc;                 // only component 0 is read
      mrow = mnew;
      #pragma unroll
      for (int df = 0; df < 4; ++df)
        #pragma unroll
        for (int r = 0; r < 4; ++r) yacc[df][r] *= resc;   // q lane-local: no shuffle
    }
    #pragma unroll
    for (int nf = 0; nf < 4; ++nf)
      #pragma unroll
      for (int r = 0; r < 4; ++r) p[nf][r] = exp2f(p[nf][r] - mrow);
    #pragma unroll
    for (int nf = 0; nf < 4; ++nf){
      uint32_t w0, w1;
      asm volatile("v_cvt_pk_bf16_f32 %0, %1, %2" : "=v"(w0) : "v"(p[nf][0]), "v"(p[nf][1]));
      asm volatile("v_cvt_pk_bf16_f32 %0, %1, %2" : "=v"(w1) : "v"(p[nf][2]), "v"(p[nf][3]));
      *(uint64_t*)(PsW + ((nf * 8 + c4 * 2) ^ pm)) = (uint64_t)w0 | ((uint64_t)w1 << 32);
    }
    asm volatile("s_waitcnt lgkmcnt(0)" ::: "memory");
    __builtin_amdgcn_sched_barrier(0);
    // PV swapped: y^T += V^T P ; sum row via ones-MFMA (replaces VALU reduce)
    __builtin_amdgcn_s_setprio(1);
    #pragma unroll
    for (int ks2 = 0; ks2 < 2; ++ks2){
      bf16x8 pf = *(const bf16x8*)(PsW + ((ks2 * 16 + c4 * 4) ^ pm));
      sacc = __builtin_amdgcn_mfma_f32_16x16x32_bf16(ones, pf, sacc, 0, 0, 0);
      #pragma unroll
      for (int df = 0; df < 4; ++df){
        int rd = df * 16 + q16, cd = ks2 * 4 + c4;
        bf16x8 vf = *(const bf16x8*)(Vs + (rd * 8 + (cd ^ (rd & 7))) * 8);
        yacc[df] = __builtin_amdgcn_mfma_f32_16x16x32_bf16(vf, pf, yacc[df], 0, 0, 0);
      }
    }
    __builtin_amdgcn_s_setprio(0);
    __builtin_amdgcn_s_barrier();
  }

  // epilogue: y[q][d] = yacc/sacc[0], all lane-local
  const float inv = 1.f / sacc[0];
  const int qq = q0 + wv * 16 + q16;
  #pragma unroll
  for (int df = 0; df < 4; ++df){
    int d0 = df * 16 + c4 * 4;
    #pragma unroll
    for (int r = 0; r < 4; ++r)
      yg[(size_t)(b * TT + qq) * 1024 + h * 64 + d0 + r] = f2b(yacc[df][r] * inv);
  }
}

// ---------------- host ----------------
extern "C" void kernel_launch(void* const* d_in, const int* in_sizes, int n_in,
                              void* d_out, int out_size, void* d_ws, size_t ws_size,
                              hipStream_t stream){
  (void)in_sizes; (void)n_in; (void)out_size; (void)ws_size;
  const float* x  = (const float*)d_in[0];
  const float* Wq = (const float*)d_in[1];
  const float* bq = (const float*)d_in[2];
  const float* Wk = (const float*)d_in[3];
  const float* bk = (const float*)d_in[4];
  const float* Wv = (const float*)d_in[5];
  const float* bv = (const float*)d_in[6];
  const float* Wo = (const float*)d_in[7];
  const float* bo = (const float*)d_in[8];
  const float* Wc = (const float*)d_in[9];
  float* out = (float*)d_out;

  char* wsb = (char*)d_ws;
  // alias plan (stream-ordered): xb dead after gemm_qkv -> yb.
  u16* xb    = (u16*)(wsb);               //  0..8M
  u16* yb    = (u16*)(wsb);               //  alias xb (attn output)
  u16* qcb   = (u16*)(wsb + (8u  << 20)); //  8..16M
  u16* kb    = (u16*)(wsb + (16u << 20)); // 16..24M
  u16* vb    = (u16*)(wsb + (24u << 20)); // 24..32M
  u16* vtb   = (u16*)(wsb + (33u << 20)); // 33..41M
  u16* WqcT  = (u16*)(wsb + (42u << 20));
  u16* WkT   = (u16*)(wsb + (44u << 20));
  u16* WvT   = (u16*)(wsb + (46u << 20));
  u16* WoT   = (u16*)(wsb + (48u << 20));
  float* bqc  = (float*)(wsb + (50u << 20));

  prep<<<7425, 256, 0, stream>>>(x, Wq, Wc, bq, Wk, Wv, Wo,
                                 xb, WqcT, WkT, WvT, WoT, bqc);
  gemm_qkv<<<dim3(8, 32, 3), 256, 0, stream>>>(xb, WqcT, WkT, WvT, bqc, bk, bv, qcb, kb, vb);
  transpose_v<<<dim3(64, 2, 32), 256, 0, stream>>>(vb, vtb);
  attn<<<dim3(2048), 128, 0, stream>>>(qcb, kb, vtb, yb);
  gemm_o<<<dim3(8, 64), 256, 0, stream>>>(yb, WoT, bo, out);
}

// Round 18
// 122.138 us; speedup vs baseline: 1.0514x; 1.0514x over previous
//
#include <hip/hip_runtime.h>
#include <stdint.h>

#define TT 2048
#define BB 2
#define MROWS (BB*TT)
#define LSCALE 0.18033688011112043f   // 0.125 * log2(e)

typedef unsigned short u16;
typedef __bf16 bf16x8 __attribute__((ext_vector_type(8)));
typedef float f32x4 __attribute__((ext_vector_type(4)));
typedef short s16x8 __attribute__((ext_vector_type(8)));
typedef unsigned short u16x4 __attribute__((ext_vector_type(4)));

#define GLOBAL_AS const __attribute__((address_space(1))) void*
#define LDS_AS __attribute__((address_space(3))) void*

__device__ __forceinline__ u16 f2b(float f){
  uint32_t u = __builtin_bit_cast(uint32_t, f);
  u = (u + 0x7FFFu + ((u >> 16) & 1u)) >> 16;
  return (u16)u;
}

// ---------------- fused prep: one dispatch, all independent blocks ----------------
__global__ __launch_bounds__(256) void prep(
    const float* __restrict__ x, const float* __restrict__ Wq,
    const float* __restrict__ Wc, const float* __restrict__ bq,
    const float* __restrict__ Wk, const float* __restrict__ Wv,
    const float* __restrict__ Wo,
    u16* __restrict__ xb, u16* __restrict__ WqcT, u16* __restrict__ WkT,
    u16* __restrict__ WvT, u16* __restrict__ WoT, float* __restrict__ bqc){
  const int i = blockIdx.x, t = threadIdx.x;
  if (i < 4096){                      // x -> bf16 (16B/thread)
    int id = i * 256 + t;
    float4 v = ((const float4*)x)[id];
    u16x4 o; o.x = f2b(v.x); o.y = f2b(v.y); o.z = f2b(v.z); o.w = f2b(v.w);
    ((u16x4*)xb)[id] = o;
    return;
  }
  if (i < 7168){                      // f32->bf16 transpose of Wk/Wv/Wo
    int j = i - 4096;
    int z = j >> 10, rem = j & 1023;
    const float* in = (z == 0) ? Wk : (z == 1) ? Wv : Wo;
    u16* out = (z == 0) ? WkT : (z == 1) ? WvT : WoT;
    __shared__ float tl[32][33];
    int tx = t & 31, ty = t >> 5;
    int c0 = (rem & 31) * 32, r0 = (rem >> 5) * 32;
    #pragma unroll
    for (int k = 0; k < 32; k += 8)
      tl[ty + k][tx] = in[(size_t)(r0 + ty + k) * 1024 + c0 + tx];
    __syncthreads();
    #pragma unroll
    for (int k = 0; k < 32; k += 8)
      out[(size_t)(c0 + ty + k) * 1024 + r0 + tx] = f2b(tl[tx][ty + k]);
    return;
  }
  __shared__ float wc[4096];          // whole Wc (64x64 f32)
  #pragma unroll
  for (int k = 0; k < 16; ++k) wc[k * 256 + t] = Wc[k * 256 + t];
  __syncthreads();
  if (i == 7424){                     // folded bias bqc = bq @ Wc-blockdiag
    #pragma unroll
    for (int k = 0; k < 4; ++k){
      int nn = t * 4 + k;
      int h = nn >> 6, lc = nn & 63;
      float a = 0.f;
      #pragma unroll
      for (int dd = 0; dd < 64; ++dd) a += bq[h * 64 + dd] * wc[dd * 64 + lc];
      bqc[nn] = a;
    }
    return;
  }
  // Wqc fold, 64d x 64n tile, written transposed: WqcT[n][d]
  __shared__ float tile[64][65];
  const int j = i - 7168;             // 0..255
  const int db = j >> 4, hb = j & 15;
  {
    int dl = t >> 2, lq = t & 3;
    const float4* wq4 = (const float4*)(Wq + (size_t)(db * 64 + dl) * 1024 + hb * 64);
    float wqr[64];
    #pragma unroll
    for (int k = 0; k < 16; ++k){
      float4 v = wq4[k];
      wqr[k * 4] = v.x; wqr[k * 4 + 1] = v.y; wqr[k * 4 + 2] = v.z; wqr[k * 4 + 3] = v.w;
    }
    #pragma unroll
    for (int jj = 0; jj < 16; ++jj){
      int lc = lq * 16 + jj;
      float a = 0.f;
      #pragma unroll
      for (int dd = 0; dd < 64; ++dd) a += wqr[dd] * wc[dd * 64 + lc];
      tile[dl][lc] = a;
    }
  }
  __syncthreads();
  {
    int nl = t >> 2, dq = t & 3;
    u16* dst = WqcT + (size_t)(hb * 64 + nl) * 1024 + db * 64 + dq * 16;
    #pragma unroll
    for (int k = 0; k < 16; ++k)
      dst[k] = f2b(tile[dq * 16 + k][nl]);
  }
}

// vt[bh][d][s] = vb[b*T + s][h*64 + d]   (bf16 -> bf16 transpose per head)
__global__ void transpose_v(const u16* __restrict__ vb, u16* __restrict__ vt){
  __shared__ u16 t[32][34];
  int tx = threadIdx.x & 31, ty = threadIdx.x >> 5;
  int s0 = blockIdx.x * 32, d0 = blockIdx.y * 32, bh = blockIdx.z;
  int b = bh >> 4, h = bh & 15;
  #pragma unroll
  for (int i = 0; i < 32; i += 8)
    t[ty + i][tx] = vb[(size_t)(b * TT + s0 + ty + i) * 1024 + h * 64 + d0 + tx];
  __syncthreads();
  #pragma unroll
  for (int i = 0; i < 32; i += 8)
    vt[((size_t)bh * 64 + d0 + ty + i) * TT + s0 + tx] = t[tx][ty + i];
}

// ---------------- 128x128 bf16 MFMA GEMM tile (m97 structure) ----------------
__device__ __forceinline__ void gemm_tile(const u16* __restrict__ A, const u16* __restrict__ BT,
                                          int m0, int n0, int K, f32x4 (&acc)[4][4],
                                          u16* As, u16* Bs, int tid){
  const int wv = tid >> 6, l = tid & 63;
  const int aoff = ((wv >> 1) * 64 + (l & 15)) * 32 + ((l >> 4) << 3);
  const int boff = ((wv & 1) * 64 + (l & 15)) * 32 + ((l >> 4) << 3);
  const int ob0 = wv * 1024 + l * 16;           // byte offset in 8KB tile
  for (int kt = 0; kt < K; kt += 32){
    __syncthreads();
    #pragma unroll
    for (int j = 0; j < 2; ++j){
      int ob = ob0 + j * 4096;
      int row = ob >> 6, col = (ob & 63) >> 1;  // col in elements (mult of 8)
      __builtin_amdgcn_global_load_lds((GLOBAL_AS)(A + (size_t)(m0 + row) * 1024 + kt + col),
                                       (LDS_AS)(As + wv * 512 + j * 2048), 16, 0, 0);
      __builtin_amdgcn_global_load_lds((GLOBAL_AS)(BT + (size_t)(n0 + row) * 1024 + kt + col),
                                       (LDS_AS)(Bs + wv * 512 + j * 2048), 16, 0, 0);
    }
    __syncthreads();
    bf16x8 av[4], bw[4];
    #pragma unroll
    for (int m = 0; m < 4; ++m) av[m] = *(const bf16x8*)(As + aoff + m * 512);
    #pragma unroll
    for (int n = 0; n < 4; ++n) bw[n] = *(const bf16x8*)(Bs + boff + n * 512);
    #pragma unroll
    for (int m = 0; m < 4; ++m)
      #pragma unroll
      for (int n = 0; n < 4; ++n)
        acc[m][n] = __builtin_amdgcn_mfma_f32_16x16x32_bf16(av[m], bw[n], acc[m][n], 0, 0, 0);
  }
}

// fused QKV projections (z: 0=Qc pre-scaled, 1=K, 2=V row-major)
__global__ __launch_bounds__(256) void gemm_qkv(
    const u16* __restrict__ xb,
    const u16* __restrict__ W0T, const u16* __restrict__ W1T, const u16* __restrict__ W2T,
    const float* __restrict__ b0, const float* __restrict__ b1, const float* __restrict__ b2,
    u16* __restrict__ o0, u16* __restrict__ o1, u16* __restrict__ o2){
  __shared__ u16 As[4096], Bs[4096];
  const int z = blockIdx.z;
  const u16* BT = (z == 0) ? W0T : (z == 1) ? W1T : W2T;
  const float* bias = (z == 0) ? b0 : (z == 1) ? b1 : b2;
  u16* Out = (z == 0) ? o0 : (z == 1) ? o1 : o2;
  const float osc = (z == 0) ? LSCALE : 1.0f;   // fold softmax scale into Q
  const int n0 = blockIdx.x * 128, m0 = blockIdx.y * 128;
  const int tid = threadIdx.x, wv = tid >> 6, l = tid & 63;
  f32x4 acc[4][4] = {};
  gemm_tile(xb, BT, m0, n0, 1024, acc, As, Bs, tid);
  const int wr = wv >> 1, wc = wv & 1;
  #pragma unroll
  for (int n = 0; n < 4; ++n){
    int col = n0 + wc * 64 + n * 16 + (l & 15);
    float bb = bias[col];
    #pragma unroll
    for (int m = 0; m < 4; ++m){
      int r0 = m0 + wr * 64 + m * 16 + ((l >> 4) << 2);
      #pragma unroll
      for (int r = 0; r < 4; ++r)
        Out[(size_t)(r0 + r) * 1024 + col] = f2b((acc[m][n][r] + bb) * osc);
    }
  }
}

// ---------------- 64x128 out-projection GEMM (2 blocks/CU occupancy fix) ------
__global__ __launch_bounds__(256) void gemm_o(
    const u16* __restrict__ A, const u16* __restrict__ BT,
    const float* __restrict__ bias, float* __restrict__ Out){
  __shared__ u16 As[2048], Bs[4096];   // 4KB A (64x32), 8KB B (128x32)
  const int n0 = blockIdx.x * 128, m0 = blockIdx.y * 64;
  const int tid = threadIdx.x, wv = tid >> 6, l = tid & 63;
  const int wr = wv >> 1, wc = wv & 1;
  const int aoff = (wr * 32 + (l & 15)) * 32 + ((l >> 4) << 3);
  const int boff = (wc * 64 + (l & 15)) * 32 + ((l >> 4) << 3);
  const int obA = wv * 1024 + l * 16;
  const int rowA = obA >> 6, colA = (obA & 63) >> 1;
  const int ob0 = wv * 1024 + l * 16;
  f32x4 acc[2][4] = {};
  for (int kt = 0; kt < 1024; kt += 32){
    __syncthreads();
    __builtin_amdgcn_global_load_lds((GLOBAL_AS)(A + (size_t)(m0 + rowA) * 1024 + kt + colA),
                                     (LDS_AS)(As + wv * 512), 16, 0, 0);
    #pragma unroll
    for (int j = 0; j < 2; ++j){
      int ob = ob0 + j * 4096;
      int row = ob >> 6, col = (ob & 63) >> 1;
      __builtin_amdgcn_global_load_lds((GLOBAL_AS)(BT + (size_t)(n0 + row) * 1024 + kt + col),
                                       (LDS_AS)(Bs + wv * 512 + j * 2048), 16, 0, 0);
    }
    __syncthreads();
    bf16x8 av[2], bw[4];
    #pragma unroll
    for (int m = 0; m < 2; ++m) av[m] = *(const bf16x8*)(As + aoff + m * 512);
    #pragma unroll
    for (int n = 0; n < 4; ++n) bw[n] = *(const bf16x8*)(Bs + boff + n * 512);
    #pragma unroll
    for (int m = 0; m < 2; ++m)
      #pragma unroll
      for (int n = 0; n < 4; ++n)
        acc[m][n] = __builtin_amdgcn_mfma_f32_16x16x32_bf16(av[m], bw[n], acc[m][n], 0, 0, 0);
  }
  #pragma unroll
  for (int n = 0; n < 4; ++n){
    int col = n0 + wc * 64 + n * 16 + (l & 15);
    float bb = bias[col];
    #pragma unroll
    for (int m = 0; m < 2; ++m){
      int r0 = m0 + wr * 32 + m * 16 + ((l >> 4) << 2);
      #pragma unroll
      for (int r = 0; r < 4; ++r)
        Out[(size_t)(r0 + r) * 1024 + col] = acc[m][n][r] + bb;
    }
  }
}

// ---------------- flash attention (causal, per (b,h)) ----------------
// BQ=64 (4 waves x 16 q-rows), BS=64, single-buffer K/V staging (24KB LDS).
// CU-load-balanced qt permutation (qtab: each CU's tile total = 66).
// bh = idx&31 keeps 4 heads per XCD (L2-resident K/V).
// Softmax sum via MFMA ones-trick (lane-local sacc); max via max chain.
__device__ const uint8_t qtab[32] = {
  31, 30, 29, 28, 27, 26, 25, 24,
   0,  1,  2,  3,  4,  5,  6,  7,
  23, 22, 21, 20, 19, 18, 17, 16,
   8,  9, 10, 11, 12, 13, 14, 15
};

__global__ __launch_bounds__(256) void attn(
    const u16* __restrict__ qcg, const u16* __restrict__ kg,
    const u16* __restrict__ vtg, u16* __restrict__ yg){
  __shared__ u16 Ks[4096], Vs[4096];   // [64 rows][8 chunks of 16B], XOR-swizzled
  __shared__ u16 Ps[4096];             // per-wave 16 q-rows x 64 s, XOR-swizzled dwords
  const int idx = blockIdx.x;
  const int qt = qtab[idx >> 5], bh = idx & 31;
  const int b = bh >> 4, h = bh & 15;
  const int q0 = qt * 64;
  const int tid = threadIdx.x, wv = tid >> 6, l = tid & 63;
  const int c4 = l >> 4, q16 = l & 15;
  const size_t base = (size_t)b * TT * 1024 + h * 64;
  const u16* Q = qcg + base;
  const u16* K = kg + base;
  const u16* Vt = vtg + (size_t)bh * 64 * TT;     // [64 d][T s]

  const int sr = tid >> 3;
  const int sc = (tid & 7) ^ (sr & 7);
  const u16* gK = K + (size_t)sr * 1024 + sc * 8;
  const u16* gV = Vt + (size_t)sr * TT + sc * 8;

  bf16x8 qf[2];
  {
    int qr = q0 + wv * 16 + q16;
    #pragma unroll
    for (int ks = 0; ks < 2; ++ks)
      qf[ks] = *(const bf16x8*)(Q + (size_t)qr * 1024 + ks * 32 + (c4 << 3));
  }
  // ones fragment for sum-via-MFMA (bf16 1.0 = 0x3F80)
  bf16x8 ones;
  {
    s16x8 o1;
    #pragma unroll
    for (int j = 0; j < 8; ++j) o1[j] = (short)0x3F80;
    ones = __builtin_bit_cast(bf16x8, o1);
  }
  f32x4 yacc[4] = {};                  // y^T: yacc[df][r] = y[q=q16][d=df*16+c4*4+r]
  f32x4 sacc = {};                     // sum row: sacc[0] = sum_s P[s][q]
  float mrow = -1e30f;                 // per-lane softmax max for q = l&15

  uint32_t* const PsW = (uint32_t*)Ps + wv * 512 + q16 * 32;
  const int pm = (q16 & 7) << 2;

  u16* const kd = Ks + wv * 512;
  u16* const vd = Vs + wv * 512;

  const int nt = qt + 1;
  for (int st = 0; st < nt; ++st){
    {
      const size_t o = (size_t)st * 64;
      __builtin_amdgcn_global_load_lds((GLOBAL_AS)(gK + o * 1024), (LDS_AS)kd, 16, 0, 0);
      __builtin_amdgcn_global_load_lds((GLOBAL_AS)(gK + (o + 32) * 1024), (LDS_AS)(kd + 2048), 16, 0, 0);
      __builtin_amdgcn_global_load_lds((GLOBAL_AS)(gV + o), (LDS_AS)vd, 16, 0, 0);
      __builtin_amdgcn_global_load_lds((GLOBAL_AS)(gV + o + 32 * TT), (LDS_AS)(vd + 2048), 16, 0, 0);
    }
    asm volatile("s_waitcnt vmcnt(0)" ::: "memory");
    __builtin_amdgcn_sched_barrier(0);
    __builtin_amdgcn_s_barrier();
    __builtin_amdgcn_sched_barrier(0);
    const int s0 = st * 64;
    f32x4 sf[4] = {};
    __builtin_amdgcn_s_setprio(1);
    #pragma unroll
    for (int ks = 0; ks < 2; ++ks)
      #pragma unroll
      for (int nf = 0; nf < 4; ++nf){
        int r = nf * 16 + q16, c = ks * 4 + c4;
        bf16x8 kf = *(const bf16x8*)(Ks + (r * 8 + (c ^ (r & 7))) * 8);
        sf[nf] = __builtin_amdgcn_mfma_f32_16x16x32_bf16(kf, qf[ks], sf[nf], 0, 0, 0);
      }
    __builtin_amdgcn_s_setprio(0);
    const int qa = q0 + wv * 16 + q16;
    float p[4][4];
    const bool domask = (st == qt);
    #pragma unroll
    for (int nf = 0; nf < 4; ++nf)
      #pragma unroll
      for (int r = 0; r < 4; ++r){
        float v_ = sf[nf][r];
        if (domask && (s0 + nf * 16 + c4 * 4 + r > qa)) v_ = -1e30f;
        p[nf][r] = v_;
      }
    // max chain
    float tmax = fmaxf(fmaxf(p[0][0], p[0][1]), p[0][2]);
    tmax = fmaxf(fmaxf(tmax, p[0][3]), p[1][0]);
    tmax = fmaxf(fmaxf(tmax, p[1][1]), p[1][2]);
    tmax = fmaxf(fmaxf(tmax, p[1][3]), p[2][0]);
    tmax = fmaxf(fmaxf(tmax, p[2][1]), p[2][2]);
    tmax = fmaxf(fmaxf(tmax, p[2][3]), p[3][0]);
    tmax = fmaxf(fmaxf(tmax, p[3][1]), p[3][2]);
    tmax = fmaxf(tmax, p[3][3]);
    tmax = fmaxf(tmax, __shfl_xor(tmax, 16));
    tmax = fmaxf(tmax, __shfl_xor(tmax, 32));
    if (__any(tmax > mrow + 8.0f)){
      float mnew = fmaxf(mrow, tmax);
      float resc = exp2f(mrow - mnew);
      sacc[0] *= resc;                 // only component 0 is read
      mrow = mnew;
      #pragma unroll
      for (int df = 0; df < 4; ++df)
        #pragma unroll
        for (int r = 0; r < 4; ++r) yacc[df][r] *= resc;   // q lane-local: no shuffle
    }
    #pragma unroll
    for (int nf = 0; nf < 4; ++nf)
      #pragma unroll
      for (int r = 0; r < 4; ++r) p[nf][r] = exp2f(p[nf][r] - mrow);
    #pragma unroll
    for (int nf = 0; nf < 4; ++nf){
      uint32_t w0, w1;
      asm volatile("v_cvt_pk_bf16_f32 %0, %1, %2" : "=v"(w0) : "v"(p[nf][0]), "v"(p[nf][1]));
      asm volatile("v_cvt_pk_bf16_f32 %0, %1, %2" : "=v"(w1) : "v"(p[nf][2]), "v"(p[nf][3]));
      *(uint64_t*)(PsW + ((nf * 8 + c4 * 2) ^ pm)) = (uint64_t)w0 | ((uint64_t)w1 << 32);
    }
    asm volatile("s_waitcnt lgkmcnt(0)" ::: "memory");
    __builtin_amdgcn_sched_barrier(0);
    // PV swapped: y^T += V^T P ; sum row via ones-MFMA (replaces VALU reduce)
    __builtin_amdgcn_s_setprio(1);
    #pragma unroll
    for (int ks2 = 0; ks2 < 2; ++ks2){
      bf16x8 pf = *(const bf16x8*)(PsW + ((ks2 * 16 + c4 * 4) ^ pm));
      sacc = __builtin_amdgcn_mfma_f32_16x16x32_bf16(ones, pf, sacc, 0, 0, 0);
      #pragma unroll
      for (int df = 0; df < 4; ++df){
        int rd = df * 16 + q16, cd = ks2 * 4 + c4;
        bf16x8 vf = *(const bf16x8*)(Vs + (rd * 8 + (cd ^ (rd & 7))) * 8);
        yacc[df] = __builtin_amdgcn_mfma_f32_16x16x32_bf16(vf, pf, yacc[df], 0, 0, 0);
      }
    }
    __builtin_amdgcn_s_setprio(0);
    __builtin_amdgcn_s_barrier();
  }

  // epilogue: y[q][d] = yacc/sacc[0], all lane-local
  const float inv = 1.f / sacc[0];
  const int qq = q0 + wv * 16 + q16;
  #pragma unroll
  for (int df = 0; df < 4; ++df){
    int d0 = df * 16 + c4 * 4;
    #pragma unroll
    for (int r = 0; r < 4; ++r)
      yg[(size_t)(b * TT + qq) * 1024 + h * 64 + d0 + r] = f2b(yacc[df][r] * inv);
  }
}

// ---------------- host ----------------
extern "C" void kernel_launch(void* const* d_in, const int* in_sizes, int n_in,
                              void* d_out, int out_size, void* d_ws, size_t ws_size,
                              hipStream_t stream){
  (void)in_sizes; (void)n_in; (void)out_size; (void)ws_size;
  const float* x  = (const float*)d_in[0];
  const float* Wq = (const float*)d_in[1];
  const float* bq = (const float*)d_in[2];
  const float* Wk = (const float*)d_in[3];
  const float* bk = (const float*)d_in[4];
  const float* Wv = (const float*)d_in[5];
  const float* bv = (const float*)d_in[6];
  const float* Wo = (const float*)d_in[7];
  const float* bo = (const float*)d_in[8];
  const float* Wc = (const float*)d_in[9];
  float* out = (float*)d_out;

  char* wsb = (char*)d_ws;
  // alias plan (stream-ordered): xb dead after gemm_qkv -> yb.
  u16* xb    = (u16*)(wsb);               //  0..8M
  u16* yb    = (u16*)(wsb);               //  alias xb (attn output)
  u16* qcb   = (u16*)(wsb + (8u  << 20)); //  8..16M
  u16* kb    = (u16*)(wsb + (16u << 20)); // 16..24M
  u16* vb    = (u16*)(wsb + (24u << 20)); // 24..32M
  u16* vtb   = (u16*)(wsb + (33u << 20)); // 33..41M
  u16* WqcT  = (u16*)(wsb + (42u << 20));
  u16* WkT   = (u16*)(wsb + (44u << 20));
  u16* WvT   = (u16*)(wsb + (46u << 20));
  u16* WoT   = (u16*)(wsb + (48u << 20));
  float* bqc  = (float*)(wsb + (50u << 20));

  prep<<<7425, 256, 0, stream>>>(x, Wq, Wc, bq, Wk, Wv, Wo,
                                 xb, WqcT, WkT, WvT, WoT, bqc);
  gemm_qkv<<<dim3(8, 32, 3), 256, 0, stream>>>(xb, WqcT, WkT, WvT, bqc, bk, bv, qcb, kb, vb);
  transpose_v<<<dim3(64, 2, 32), 256, 0, stream>>>(vb, vtb);
  attn<<<dim3(1024), 256, 0, stream>>>(qcb, kb, vtb, yb);
  gemm_o<<<dim3(8, 64), 256, 0, stream>>>(yb, WoT, bo, out);
}